// Round 8
// baseline (175.400 us; speedup 1.0000x reference)
//
#include <hip/hip_runtime.h>

typedef __attribute__((ext_vector_type(8))) __bf16 bf16x8;
typedef __attribute__((ext_vector_type(8))) unsigned short ushort8;
typedef __attribute__((ext_vector_type(4))) float floatx4;
typedef __attribute__((ext_vector_type(16))) float floatx16;

__device__ __forceinline__ unsigned short f2bf(float f) {
    unsigned int u = __builtin_bit_cast(unsigned int, f);
    unsigned int r = u + 0x7FFFu + ((u >> 16) & 1u);
    return (unsigned short)(r >> 16);
}
__device__ __forceinline__ float bf2f(unsigned short h) {
    return __builtin_bit_cast(float, ((unsigned int)h) << 16);
}

// Prep: augmented codebook wext[512][80] bf16: cols 0..63 = -2w, 64 = ||w||^2 hi,
// 65 = residual, 66..79 = 0. Score = MFMA(A_ext, [x|1|1|0..]) = ||w||^2 - 2<w,x>.
__global__ void vq_prep(const float* __restrict__ w, unsigned short* __restrict__ wext) {
    const int t = threadIdx.x;
    const int row = blockIdx.x * 4 + (t >> 6);
    const int c = t & 63;
    float v = w[row * 64 + c];
    wext[row * 80 + c] = f2bf(-2.f * v);
    float s = v * v;
#pragma unroll
    for (int off = 32; off; off >>= 1) s += __shfl_xor(s, off, 64);
    if (c == 0) {
        const unsigned short hi = f2bf(s);
        wext[row * 80 + 64] = hi;
        wext[row * 80 + 65] = f2bf(s - bf2f(hi));
    }
    if (c >= 2 && c < 16) wext[row * 80 + 64 + c] = 0;
}

// Phase 1: scores + argmin + loss partials. Launched 5x this round (idempotent)
// so its duration is measurable via dur_us delta: A = (dur_R8 - dur_R7)/4.
__global__ void __launch_bounds__(256) vq_argmin(
    const float* __restrict__ in,             // [32][64][4096]
    const unsigned short* __restrict__ wext,  // [512][80]
    unsigned short* __restrict__ idxout,      // [131072]
    float* __restrict__ partials) {           // [1024]
    __shared__ unsigned short xs[2][2048];
    __shared__ float red[2][4][32];           // parity banks -> 1 barrier/tile
    __shared__ float ws4[4];

    const int t = threadIdx.x;
    const int lane = t & 63;
    const int wv = t >> 6;
    const int bid = blockIdx.x;
    const int col = lane & 31;
    const int hi = lane >> 5;

    // stationary A-fragments: 4 code-tiles x 5 k-chunks
    bf16x8 A[4][5];
#pragma unroll
    for (int i = 0; i < 4; ++i) {
        const int row = (wv * 4 + i) * 32 + col;
#pragma unroll
        for (int ch = 0; ch < 5; ++ch)
            A[i][ch] = *(const bf16x8*)&wext[row * 80 + ch * 16 + hi * 8];
    }
    ushort8 b4u = {0, 0, 0, 0, 0, 0, 0, 0};
    if (hi == 0) { b4u[0] = 0x3F80; b4u[1] = 0x3F80; }
    const bf16x8 Bf4 = __builtin_bit_cast(bf16x8, b4u);

    float x2acc = 0.f;
    float smin_acc = 0.f;

    {   // stage tile 0
        const int gt = bid * 4;
        const float* in_base = in + ((size_t)(gt >> 7) * 64) * 4096 + ((gt & 127) << 5);
#pragma unroll
        for (int it = 0; it < 2; ++it) {
            const int task = t + 256 * it;
            const int c = task >> 3, q = task & 7, p0 = q * 4;
            floatx4 v = *(const floatx4*)(in_base + (size_t)c * 4096 + p0);
            x2acc += v[0] * v[0] + v[1] * v[1] + v[2] * v[2] + v[3] * v[3];
            unsigned short* p = &xs[0][((c >> 3) * 32 + p0) * 8 + (c & 7)];
            p[0] = f2bf(v[0]); p[8] = f2bf(v[1]); p[16] = f2bf(v[2]); p[24] = f2bf(v[3]);
        }
    }
    __syncthreads();

#pragma unroll
    for (int ti = 0; ti < 4; ++ti) {
        const int cur = ti & 1;
        const int par = ti & 1;
        const int gt = bid * 4 + ti;

        bf16x8 Bf[4];
#pragma unroll
        for (int ch = 0; ch < 4; ++ch)
            Bf[ch] = *(const bf16x8*)&xs[cur][((2 * ch + hi) * 32 + col) * 8];

        if (ti < 3) {  // stage next tile (before the single barrier)
            const int gn = gt + 1;
            const float* in_base = in + ((size_t)(gn >> 7) * 64) * 4096 + ((gn & 127) << 5);
#pragma unroll
            for (int it = 0; it < 2; ++it) {
                const int task = t + 256 * it;
                const int c = task >> 3, q = task & 7, p0 = q * 4;
                floatx4 v = *(const floatx4*)(in_base + (size_t)c * 4096 + p0);
                x2acc += v[0] * v[0] + v[1] * v[1] + v[2] * v[2] + v[3] * v[3];
                unsigned short* p = &xs[cur ^ 1][((c >> 3) * 32 + p0) * 8 + (c & 7)];
                p[0] = f2bf(v[0]); p[8] = f2bf(v[1]); p[16] = f2bf(v[2]); p[24] = f2bf(v[3]);
            }
        }

        float best = 1e30f;
#pragma unroll
        for (int i = 0; i < 4; ++i) {
            floatx16 acc = {0.f, 0.f, 0.f, 0.f, 0.f, 0.f, 0.f, 0.f,
                            0.f, 0.f, 0.f, 0.f, 0.f, 0.f, 0.f, 0.f};
            acc = __builtin_amdgcn_mfma_f32_32x32x16_bf16(A[i][0], Bf[0], acc, 0, 0, 0);
            acc = __builtin_amdgcn_mfma_f32_32x32x16_bf16(A[i][1], Bf[1], acc, 0, 0, 0);
            acc = __builtin_amdgcn_mfma_f32_32x32x16_bf16(A[i][2], Bf[2], acc, 0, 0, 0);
            acc = __builtin_amdgcn_mfma_f32_32x32x16_bf16(A[i][3], Bf[3], acc, 0, 0, 0);
            acc = __builtin_amdgcn_mfma_f32_32x32x16_bf16(A[i][4], Bf4,   acc, 0, 0, 0);
            const int code_base = (wv * 4 + i) * 32;
            float pk[16];
#pragma unroll
            for (int q = 0; q < 4; ++q) {
#pragma unroll
                for (int rr = 0; rr < 4; ++rr) {
                    const int r = q * 4 + rr;
                    const unsigned int code = (unsigned int)(code_base + 8 * q + 4 * hi + rr);
                    pk[r] = __builtin_bit_cast(float,
                        (__builtin_bit_cast(unsigned int, acc[r]) & 0xFFFFFE00u) | code);
                }
            }
            // min3-friendly tree: 16 -> 6 -> 2 -> 1 (8 ops)
            float m0 = fminf(fminf(pk[0], pk[1]), pk[2]);
            float m1 = fminf(fminf(pk[3], pk[4]), pk[5]);
            float m2 = fminf(fminf(pk[6], pk[7]), pk[8]);
            float m3 = fminf(fminf(pk[9], pk[10]), pk[11]);
            float m4 = fminf(fminf(pk[12], pk[13]), pk[14]);
            float m5 = fminf(fminf(m0, m1), m2);
            float m6 = fminf(fminf(m3, m4), pk[15]);
            best = fminf(best, fminf(m5, m6));
        }
        best = fminf(best, __shfl_xor(best, 32, 64));
        if (lane < 32) red[par][wv][col] = best;
        __syncthreads();  // single barrier: covers red writes AND next-tile staging

        if (wv == 0 && lane < 32) {
            const float v = fminf(fminf(red[par][0][col], red[par][1][col]),
                                  fminf(red[par][2][col], red[par][3][col]));
            smin_acc += __builtin_bit_cast(float,
                __builtin_bit_cast(unsigned int, v) & 0xFFFFFE00u);
            idxout[gt * 32 + col] =
                (unsigned short)(__builtin_bit_cast(unsigned int, v) & 511u);
        }
        // no trailing barrier: next tile writes red[par^1]; wv0's reads of
        // red[par] complete before wv0 itself reaches the next barrier.
    }

    float tot = x2acc + ((wv == 0 && lane < 32) ? smin_acc : 0.f);
#pragma unroll
    for (int off = 1; off < 64; off <<= 1) tot += __shfl_xor(tot, off, 64);
    if (lane == 0) ws4[wv] = tot;
    __syncthreads();
    if (t == 0) partials[bid] = ws4[0] + ws4[1] + ws4[2] + ws4[3];
}

// Phase 2: gather + write. Row-contiguous gathers, LDS transpose, contiguous writes.
__global__ void __launch_bounds__(256) vq_gather(
    const unsigned short* __restrict__ idx,  // [131072] = [32][4096]
    const float* __restrict__ w,             // [512][64]
    float* __restrict__ out) {               // [32][64][4096]
    __shared__ float g[128][65];
    __shared__ unsigned short idxs[128];

    const int t = threadIdx.x;
    const int bid = blockIdx.x;
    const int b = bid >> 5;
    const int p0 = (bid & 31) << 7;

    if (t < 128) idxs[t] = idx[b * 4096 + p0 + t];
    __syncthreads();

    const int c0 = (t & 15) * 4;
    const int rsub = t >> 4;
#pragma unroll
    for (int pass = 0; pass < 8; ++pass) {
        const int r = pass * 16 + rsub;
        const int code = idxs[r];
        *(floatx4*)&g[r][c0] = *(const floatx4*)(w + code * 64 + c0);
    }
    __syncthreads();

    const int c = t >> 2;
    const int q = t & 3;
    float* ob = out + ((size_t)b * 64 + c) * 4096 + p0 + q * 32;
#pragma unroll
    for (int k = 0; k < 8; ++k) {
        const int p = q * 32 + k * 4;
        floatx4 v = {g[p][c], g[p + 1][c], g[p + 2][c], g[p + 3][c]};
        *(floatx4*)(ob + k * 4) = v;
    }
}

// Final: sum 1024 per-block partials -> scalar loss.
__global__ void vq_reduce(const float* __restrict__ partials, float* __restrict__ loss) {
    const int t = threadIdx.x;
    float s = partials[t] + partials[t + 256] + partials[t + 512] + partials[t + 768];
#pragma unroll
    for (int off = 32; off; off >>= 1) s += __shfl_xor(s, off, 64);
    __shared__ float ws4[4];
    if ((t & 63) == 0) ws4[t >> 6] = s;
    __syncthreads();
    if (t == 0) loss[0] = (ws4[0] + ws4[1] + ws4[2] + ws4[3]) * (1.25f / 8388608.f);
}

extern "C" void kernel_launch(void* const* d_in, const int* in_sizes, int n_in,
                              void* d_out, int out_size, void* d_ws, size_t ws_size,
                              hipStream_t stream) {
    const float* in = (const float*)d_in[0];
    const float* w  = (const float*)d_in[1];
    float* out = (float*)d_out;
    float* loss = out + 8388608;  // second output (scalar), concatenated
    unsigned short* wext = (unsigned short*)d_ws;                     // 80 KB
    float* partials = (float*)((char*)d_ws + 81920);                  // 4 KB
    unsigned short* idxbuf = (unsigned short*)((char*)d_ws + 86016);  // 256 KB

    vq_prep<<<128, 256, 0, stream>>>(w, wext);
    // MEASUREMENT: argmin x5 (idempotent). A = (dur_R8 - dur_R7) / 4.
    vq_argmin<<<1024, 256, 0, stream>>>(in, wext, idxbuf, partials);
    vq_argmin<<<1024, 256, 0, stream>>>(in, wext, idxbuf, partials);
    vq_argmin<<<1024, 256, 0, stream>>>(in, wext, idxbuf, partials);
    vq_argmin<<<1024, 256, 0, stream>>>(in, wext, idxbuf, partials);
    vq_argmin<<<1024, 256, 0, stream>>>(in, wext, idxbuf, partials);
    vq_gather<<<1024, 256, 0, stream>>>(idxbuf, w, out);
    vq_reduce<<<1, 256, 0, stream>>>(partials, loss);
}

// Round 9
// 102.485 us; speedup vs baseline: 1.7115x; 1.7115x over previous
//
#include <hip/hip_runtime.h>

typedef __attribute__((ext_vector_type(8))) __bf16 bf16x8;
typedef __attribute__((ext_vector_type(8))) unsigned short ushort8;
typedef __attribute__((ext_vector_type(4))) float floatx4;
typedef __attribute__((ext_vector_type(16))) float floatx16;

__device__ __forceinline__ unsigned short f2bf(float f) {
    unsigned int u = __builtin_bit_cast(unsigned int, f);
    unsigned int r = u + 0x7FFFu + ((u >> 16) & 1u);
    return (unsigned short)(r >> 16);
}
__device__ __forceinline__ float bf2f(unsigned short h) {
    return __builtin_bit_cast(float, ((unsigned int)h) << 16);
}

// Prep: augmented codebook wext[512][80] bf16: cols 0..63 = -2w, 64 = ||w||^2 hi,
// 65 = residual, 66..79 = 0. Score = MFMA(A_ext, [x|1|1|0..]) = ||w||^2 - 2<w,x>.
__global__ void vq_prep(const float* __restrict__ w, unsigned short* __restrict__ wext) {
    const int t = threadIdx.x;
    const int row = blockIdx.x * 4 + (t >> 6);
    const int c = t & 63;
    float v = w[row * 64 + c];
    wext[row * 80 + c] = f2bf(-2.f * v);
    float s = v * v;
#pragma unroll
    for (int off = 32; off; off >>= 1) s += __shfl_xor(s, off, 64);
    if (c == 0) {
        const unsigned short hi = f2bf(s);
        wext[row * 80 + 64] = hi;
        wext[row * 80 + 65] = f2bf(s - bf2f(hi));
    }
    if (c >= 2 && c < 16) wext[row * 80 + 64 + c] = 0;
}

// Phase 1: scores + argmin + loss partials (measured: 16.3 us in R8).
__global__ void __launch_bounds__(256) vq_argmin(
    const float* __restrict__ in,             // [32][64][4096]
    const unsigned short* __restrict__ wext,  // [512][80]
    unsigned short* __restrict__ idxout,      // [131072]
    float* __restrict__ partials) {           // [1024]
    __shared__ unsigned short xs[2][2048];
    __shared__ float red[2][4][32];           // parity banks -> 1 barrier/tile
    __shared__ float ws4[4];

    const int t = threadIdx.x;
    const int lane = t & 63;
    const int wv = t >> 6;
    const int bid = blockIdx.x;
    const int col = lane & 31;
    const int hi = lane >> 5;

    bf16x8 A[4][5];
#pragma unroll
    for (int i = 0; i < 4; ++i) {
        const int row = (wv * 4 + i) * 32 + col;
#pragma unroll
        for (int ch = 0; ch < 5; ++ch)
            A[i][ch] = *(const bf16x8*)&wext[row * 80 + ch * 16 + hi * 8];
    }
    ushort8 b4u = {0, 0, 0, 0, 0, 0, 0, 0};
    if (hi == 0) { b4u[0] = 0x3F80; b4u[1] = 0x3F80; }
    const bf16x8 Bf4 = __builtin_bit_cast(bf16x8, b4u);

    float x2acc = 0.f;
    float smin_acc = 0.f;

    {   // stage tile 0
        const int gt = bid * 4;
        const float* in_base = in + ((size_t)(gt >> 7) * 64) * 4096 + ((gt & 127) << 5);
#pragma unroll
        for (int it = 0; it < 2; ++it) {
            const int task = t + 256 * it;
            const int c = task >> 3, q = task & 7, p0 = q * 4;
            floatx4 v = *(const floatx4*)(in_base + (size_t)c * 4096 + p0);
            x2acc += v[0] * v[0] + v[1] * v[1] + v[2] * v[2] + v[3] * v[3];
            unsigned short* p = &xs[0][((c >> 3) * 32 + p0) * 8 + (c & 7)];
            p[0] = f2bf(v[0]); p[8] = f2bf(v[1]); p[16] = f2bf(v[2]); p[24] = f2bf(v[3]);
        }
    }
    __syncthreads();

#pragma unroll
    for (int ti = 0; ti < 4; ++ti) {
        const int cur = ti & 1;
        const int par = ti & 1;
        const int gt = bid * 4 + ti;

        bf16x8 Bf[4];
#pragma unroll
        for (int ch = 0; ch < 4; ++ch)
            Bf[ch] = *(const bf16x8*)&xs[cur][((2 * ch + hi) * 32 + col) * 8];

        if (ti < 3) {
            const int gn = gt + 1;
            const float* in_base = in + ((size_t)(gn >> 7) * 64) * 4096 + ((gn & 127) << 5);
#pragma unroll
            for (int it = 0; it < 2; ++it) {
                const int task = t + 256 * it;
                const int c = task >> 3, q = task & 7, p0 = q * 4;
                floatx4 v = *(const floatx4*)(in_base + (size_t)c * 4096 + p0);
                x2acc += v[0] * v[0] + v[1] * v[1] + v[2] * v[2] + v[3] * v[3];
                unsigned short* p = &xs[cur ^ 1][((c >> 3) * 32 + p0) * 8 + (c & 7)];
                p[0] = f2bf(v[0]); p[8] = f2bf(v[1]); p[16] = f2bf(v[2]); p[24] = f2bf(v[3]);
            }
        }

        float best = 1e30f;
#pragma unroll
        for (int i = 0; i < 4; ++i) {
            floatx16 acc = {0.f, 0.f, 0.f, 0.f, 0.f, 0.f, 0.f, 0.f,
                            0.f, 0.f, 0.f, 0.f, 0.f, 0.f, 0.f, 0.f};
            acc = __builtin_amdgcn_mfma_f32_32x32x16_bf16(A[i][0], Bf[0], acc, 0, 0, 0);
            acc = __builtin_amdgcn_mfma_f32_32x32x16_bf16(A[i][1], Bf[1], acc, 0, 0, 0);
            acc = __builtin_amdgcn_mfma_f32_32x32x16_bf16(A[i][2], Bf[2], acc, 0, 0, 0);
            acc = __builtin_amdgcn_mfma_f32_32x32x16_bf16(A[i][3], Bf[3], acc, 0, 0, 0);
            acc = __builtin_amdgcn_mfma_f32_32x32x16_bf16(A[i][4], Bf4,   acc, 0, 0, 0);
            const int code_base = (wv * 4 + i) * 32;
            float pk[16];
#pragma unroll
            for (int q = 0; q < 4; ++q) {
#pragma unroll
                for (int rr = 0; rr < 4; ++rr) {
                    const int r = q * 4 + rr;
                    const unsigned int code = (unsigned int)(code_base + 8 * q + 4 * hi + rr);
                    pk[r] = __builtin_bit_cast(float,
                        (__builtin_bit_cast(unsigned int, acc[r]) & 0xFFFFFE00u) | code);
                }
            }
            float m0 = fminf(fminf(pk[0], pk[1]), pk[2]);
            float m1 = fminf(fminf(pk[3], pk[4]), pk[5]);
            float m2 = fminf(fminf(pk[6], pk[7]), pk[8]);
            float m3 = fminf(fminf(pk[9], pk[10]), pk[11]);
            float m4 = fminf(fminf(pk[12], pk[13]), pk[14]);
            float m5 = fminf(fminf(m0, m1), m2);
            float m6 = fminf(fminf(m3, m4), pk[15]);
            best = fminf(best, fminf(m5, m6));
        }
        best = fminf(best, __shfl_xor(best, 32, 64));
        if (lane < 32) red[par][wv][col] = best;
        __syncthreads();

        if (wv == 0 && lane < 32) {
            const float v = fminf(fminf(red[par][0][col], red[par][1][col]),
                                  fminf(red[par][2][col], red[par][3][col]));
            smin_acc += __builtin_bit_cast(float,
                __builtin_bit_cast(unsigned int, v) & 0xFFFFFE00u);
            idxout[gt * 32 + col] =
                (unsigned short)(__builtin_bit_cast(unsigned int, v) & 511u);
        }
    }

    float tot = x2acc + ((wv == 0 && lane < 32) ? smin_acc : 0.f);
#pragma unroll
    for (int off = 1; off < 64; off <<= 1) tot += __shfl_xor(tot, off, 64);
    if (lane == 0) ws4[wv] = tot;
    __syncthreads();
    if (t == 0) partials[bid] = ws4[0] + ws4[1] + ws4[2] + ws4[3];
}

// Phase 2: gather + write. Write phase now emits per-instruction-contiguous
// 2x512B segments (lanes 0-31 -> channel c, lanes 32-63 -> channel c+1).
__global__ void __launch_bounds__(256) vq_gather(
    const unsigned short* __restrict__ idx,  // [131072] = [32][4096]
    const float* __restrict__ w,             // [512][64]
    float* __restrict__ out) {               // [32][64][4096]
    __shared__ float g[128][65];
    __shared__ unsigned short idxs[128];

    const int t = threadIdx.x;
    const int lane = t & 63;
    const int wv = t >> 6;
    const int bid = blockIdx.x;
    const int b = bid >> 5;
    const int p0 = (bid & 31) << 7;

    if (t < 128) idxs[t] = idx[b * 4096 + p0 + t];
    __syncthreads();

    // gather: 16 lanes per code row (full 256B row contiguous)
    const int c0 = (t & 15) * 4;
    const int rsub = t >> 4;
#pragma unroll
    for (int pass = 0; pass < 8; ++pass) {
        const int r = pass * 16 + rsub;
        const int code = idxs[r];
        *(floatx4*)&g[r][c0] = *(const floatx4*)(w + code * 64 + c0);
    }
    __syncthreads();

    // write: per k, wave covers 2 channels; each half-wave writes one channel's
    // full 128-position run (512B contiguous per 32-lane group).
    const int p = (lane & 31) * 4;
    const int ch_half = lane >> 5;
#pragma unroll
    for (int k = 0; k < 8; ++k) {
        const int c = wv * 16 + k * 2 + ch_half;
        floatx4 v = {g[p][c], g[p + 1][c], g[p + 2][c], g[p + 3][c]};
        *(floatx4*)(out + ((size_t)b * 64 + c) * 4096 + p0 + p) = v;
    }
}

// Final: sum 1024 per-block partials -> scalar loss.
__global__ void vq_reduce(const float* __restrict__ partials, float* __restrict__ loss) {
    const int t = threadIdx.x;
    float s = partials[t] + partials[t + 256] + partials[t + 512] + partials[t + 768];
#pragma unroll
    for (int off = 32; off; off >>= 1) s += __shfl_xor(s, off, 64);
    __shared__ float ws4[4];
    if ((t & 63) == 0) ws4[t >> 6] = s;
    __syncthreads();
    if (t == 0) loss[0] = (ws4[0] + ws4[1] + ws4[2] + ws4[3]) * (1.25f / 8388608.f);
}

extern "C" void kernel_launch(void* const* d_in, const int* in_sizes, int n_in,
                              void* d_out, int out_size, void* d_ws, size_t ws_size,
                              hipStream_t stream) {
    const float* in = (const float*)d_in[0];
    const float* w  = (const float*)d_in[1];
    float* out = (float*)d_out;
    float* loss = out + 8388608;  // second output (scalar), concatenated
    unsigned short* wext = (unsigned short*)d_ws;                     // 80 KB
    float* partials = (float*)((char*)d_ws + 81920);                  // 4 KB
    unsigned short* idxbuf = (unsigned short*)((char*)d_ws + 86016);  // 256 KB

    vq_prep<<<128, 256, 0, stream>>>(w, wext);
    vq_argmin<<<1024, 256, 0, stream>>>(in, wext, idxbuf, partials);
    vq_gather<<<1024, 256, 0, stream>>>(idxbuf, w, out);
    vq_reduce<<<1, 256, 0, stream>>>(partials, loss);
}